// Round 1
// baseline (148.627 us; speedup 1.0000x reference)
//
#include <hip/hip_runtime.h>
#include <math.h>

// Problem: BoundaryLoss — B=32, C=1, H=W=512, fp32 pred + binary fp32 target.
// loss = mean( bce(sigmoid(pred), target) * (1 + 4*boundary) )
// boundary = (boxsum5(target) > 0) - (boxsum5(target) == 25), zero-padded.
//
// Fused single pass: separable 5x5 box sum (horizontal via LDS line buffer,
// vertical via per-thread ring), BCE via one softplus (t is exactly 0/1):
//   bce = min(softplus((1-2t)*x), 100)   [matches torch's log-clamp at -100]

constexpr int B = 32, H = 512, W = 512;
constexpr int RS = 32;                 // rows per block strip
constexpr int STRIPS = H / RS;         // 16
constexpr int NBLK = B * STRIPS;       // 512 blocks
constexpr float INV_N = 1.0f / (float)((long long)B * H * W);

__device__ __forceinline__ float bce_sp(float x, float t) {
    // t is exactly 0.0f or 1.0f
    float y = (t > 0.5f) ? -x : x;
    float sp = fmaxf(y, 0.0f) + log1pf(expf(-fabsf(y)));
    return fminf(sp, 100.0f);
}

__global__ __launch_bounds__(256, 2) void bl_main(
    const float* __restrict__ pred, const float* __restrict__ tgt,
    float* __restrict__ partials)
{
    // Double-buffered line buffer: [2..513] live data, [0..1] and [514..515] zero pad.
    __shared__ float rowbuf[2][W + 8];
    const int tid = threadIdx.x;
    const int b  = blockIdx.x / STRIPS;
    const int r0 = (blockIdx.x % STRIPS) * RS;
    const float* tb = tgt  + (size_t)b * H * W;
    const float* pb = pred + (size_t)b * H * W;
    const int c = 2 * tid;             // each thread owns 2 columns

    if (tid < 2) {
        rowbuf[0][tid] = 0.0f;          rowbuf[1][tid] = 0.0f;
        rowbuf[0][W + 2 + tid] = 0.0f;  rowbuf[1][W + 2 + tid] = 0.0f;
    }
    __syncthreads();

    float ringA[5], ringB[5], tA[5], tB[5];   // vertical window rings
    float acc = 0.0f;

#pragma unroll
    for (int i = 0; i < RS + 4; ++i) {
        const int r = r0 - 2 + i;
        float tx = 0.0f, ty = 0.0f;
        if (r >= 0 && r < H) {
            float2 tv = *(const float2*)(tb + r * W + c);
            tx = tv.x; ty = tv.y;
        }
        float* buf = rowbuf[i & 1];
        buf[2 + c] = tx;
        buf[3 + c] = ty;
        __syncthreads();
        // horizontal 5-tap for both owned columns (6 LDS reads, stride-2: free 2-way)
        float v0 = buf[c + 0], v1 = buf[c + 1], v2 = buf[c + 2],
              v3 = buf[c + 3], v4 = buf[c + 4], v5 = buf[c + 5];
        ringA[i % 5] = v0 + v1 + v2 + v3 + v4;
        ringB[i % 5] = v1 + v2 + v3 + v4 + v5;
        tA[i % 5] = tx;
        tB[i % 5] = ty;

        if (i >= 4) {
            const int ro = r0 + i - 4;          // output row (center of window)
            float s0 = ringA[0] + ringA[1] + ringA[2] + ringA[3] + ringA[4];
            float s1 = ringB[0] + ringB[1] + ringB[2] + ringB[3] + ringB[4];
            float2 pv = *(const float2*)(pb + ro * W + c);
            float t0 = tA[(i - 2) % 5], t1 = tB[(i - 2) % 5];
            // boundary: s in {1..24} -> weight 5, else (s==0 or s==25) -> 1
            float w0 = (s0 > 0.5f && s0 < 24.5f) ? 5.0f : 1.0f;
            float w1 = (s1 > 0.5f && s1 < 24.5f) ? 5.0f : 1.0f;
            acc += w0 * bce_sp(pv.x, t0) + w1 * bce_sp(pv.y, t1);
        }
        // next iteration writes the other buffer; the barrier above orders
        // this iteration's reads against the i+2 overwrite.
    }

    // wave64 shuffle reduce, then cross-wave via LDS
    #pragma unroll
    for (int off = 32; off > 0; off >>= 1)
        acc += __shfl_down(acc, off, 64);
    __shared__ float wsum[4];
    if ((tid & 63) == 0) wsum[tid >> 6] = acc;
    __syncthreads();
    if (tid == 0)
        partials[blockIdx.x] = wsum[0] + wsum[1] + wsum[2] + wsum[3];
}

__global__ __launch_bounds__(256) void bl_final(
    const float* __restrict__ partials, float* __restrict__ out)
{
    const int tid = threadIdx.x;
    float v = partials[tid] + partials[tid + 256];   // NBLK == 512
    #pragma unroll
    for (int off = 32; off > 0; off >>= 1)
        v += __shfl_down(v, off, 64);
    __shared__ float wsum[4];
    if ((tid & 63) == 0) wsum[tid >> 6] = v;
    __syncthreads();
    if (tid == 0)
        out[0] = (wsum[0] + wsum[1] + wsum[2] + wsum[3]) * INV_N;
}

extern "C" void kernel_launch(void* const* d_in, const int* in_sizes, int n_in,
                              void* d_out, int out_size, void* d_ws, size_t ws_size,
                              hipStream_t stream) {
    const float* pred = (const float*)d_in[0];
    const float* tgt  = (const float*)d_in[1];
    float* partials = (float*)d_ws;       // NBLK floats, fully written before read
    float* out = (float*)d_out;

    bl_main<<<NBLK, 256, 0, stream>>>(pred, tgt, partials);
    bl_final<<<1, 256, 0, stream>>>(partials, out);
}

// Round 2
// 98.283 us; speedup vs baseline: 1.5122x; 1.5122x over previous
//
#include <hip/hip_runtime.h>
#include <math.h>

// BoundaryLoss — B=32, C=1, H=W=512 fp32. loss = mean(bce(sigmoid(pred),t) * (1+4*boundary)),
// boundary = (boxsum5(t)>0) - (boxsum5(t)==25), zero padding.
//
// R2 design: wave-autonomous, ZERO block barriers in the hot path.
//  - lane owns 8 contiguous cols (64 lanes = full W=512), 2x float4 loads/row
//  - target is binary -> pack 8 cols as 1 byte/col in a uint64
//  - horizontal 5-tap: byte-wise shifted adds; 2-col halo via __shfl (no LDS)
//  - vertical 5-tap: ring of 5 packed uint64 (10 VGPRs, no carries: max 25 < 255)
//  - bce = min(softplus((1-2t)x),100), fast __expf/__logf (abs err ~1e-5 << 0.08 thr)
//  - 4 rows/wave -> 4096 waves / 1024 blocks -> 4 blocks/CU for latency hiding

typedef unsigned long long u64;

constexpr int NB = 32, H = 512, W = 512;
constexpr int RPW = 4;                   // output rows per wave
constexpr int SPI = H / RPW;             // 128 strips per image
constexpr int WPB = 4;                   // waves per block
constexpr int NBLK = NB * SPI / WPB;     // 1024 blocks
constexpr float INV_N = 1.0f / (float)(NB * H * W);

__device__ __forceinline__ u64 pack8(float4 a, float4 b) {
    // t in {0.0f, 1.0f}: 1.0f = 0x3F800000 (bit 23), 0.0f = 0. Extract bit23 -> byte lane.
    unsigned a0 = __float_as_uint(a.x), a1 = __float_as_uint(a.y),
             a2 = __float_as_uint(a.z), a3 = __float_as_uint(a.w);
    unsigned b0 = __float_as_uint(b.x), b1 = __float_as_uint(b.y),
             b2 = __float_as_uint(b.z), b3 = __float_as_uint(b.w);
    unsigned lo = ((a0 >> 23) & 0x1u)      | ((a1 >> 15) & 0x100u)
                | ((a2 >> 7)  & 0x10000u)  | ((a3 << 1)  & 0x1000000u);
    unsigned hi = ((b0 >> 23) & 0x1u)      | ((b1 >> 15) & 0x100u)
                | ((b2 >> 7)  & 0x10000u)  | ((b3 << 1)  & 0x1000000u);
    return (u64)lo | ((u64)hi << 32);
}

__device__ __forceinline__ float bce_one(float x, unsigned tbit, unsigned s) {
    float y = tbit ? -x : x;                       // t==1 -> softplus(-x), t==0 -> softplus(x)
    float sp = fmaxf(y, 0.0f) + __logf(1.0f + __expf(-fabsf(y)));
    float w = (s - 1u) < 24u ? 5.0f : 1.0f;        // s==0 or s==25 -> 1, else 5
    return w * fminf(sp, 100.0f);
}

__global__ __launch_bounds__(256, 4) void bl_main(
    const float* __restrict__ pred, const float* __restrict__ tgt,
    float* __restrict__ partials)
{
    const int tid  = threadIdx.x;
    const int lane = tid & 63;
    const int widx = tid >> 6;
    const int g    = blockIdx.x * WPB + widx;       // global wave id, 0..4095
    const int b    = g >> 7;                        // g / SPI
    const int r0   = (g & (SPI - 1)) * RPW;
    const int c    = lane * 8;
    const float* tb = tgt  + (size_t)b * H * W;
    const float* pb = pred + (size_t)b * H * W;

    u64 hring[5], vring[5];
    float acc = 0.0f;

#pragma unroll
    for (int i = 0; i < RPW + 4; ++i) {
        const int r = r0 - 2 + i;                   // wave-uniform
        u64 v = 0;
        if ((unsigned)r < (unsigned)H) {
            const float4* tp = (const float4*)(tb + (size_t)r * W + c);
            float4 ta = tp[0], tb2 = tp[1];
            v = pack8(ta, tb2);
        }
        u64 lv = __shfl_up(v, 1, 64);
        u64 rv = __shfl_down(v, 1, 64);
        if (lane == 0)  lv = 0;                     // image left edge: zero pad
        if (lane == 63) rv = 0;                     // image right edge
        // horizontal 5-tap box sum, byte-wise (each byte <= 5, no carry)
        u64 h = v + ((v << 8) | (lv >> 56)) + ((v << 16) | (lv >> 48))
                  + ((v >> 8) | (rv << 56)) + ((v >> 16) | (rv << 48));
        hring[i % 5] = h;
        vring[i % 5] = v;

        if (i >= 4) {
            const int ro = r0 + i - 4;              // output row
            u64 S  = hring[0] + hring[1] + hring[2] + hring[3] + hring[4]; // bytes <= 25
            u64 vc = vring[(i + 3) % 5];            // target row ro, loaded at i-2
            const float4* pp = (const float4*)(pb + (size_t)ro * W + c);
            float4 p0 = pp[0], p1 = pp[1];
            unsigned vl = (unsigned)vc,         Sl = (unsigned)S;
            unsigned vh = (unsigned)(vc >> 32), Sh = (unsigned)(S >> 32);
            acc += bce_one(p0.x,  vl        & 1u,  Sl        & 0xFFu);
            acc += bce_one(p0.y, (vl >>  8) & 1u, (Sl >>  8) & 0xFFu);
            acc += bce_one(p0.z, (vl >> 16) & 1u, (Sl >> 16) & 0xFFu);
            acc += bce_one(p0.w, (vl >> 24) & 1u, (Sl >> 24) & 0xFFu);
            acc += bce_one(p1.x,  vh        & 1u,  Sh        & 0xFFu);
            acc += bce_one(p1.y, (vh >>  8) & 1u, (Sh >>  8) & 0xFFu);
            acc += bce_one(p1.z, (vh >> 16) & 1u, (Sh >> 16) & 0xFFu);
            acc += bce_one(p1.w, (vh >> 24) & 1u, (Sh >> 24) & 0xFFu);
        }
    }

    // wave reduce, then one LDS hop per block (the only barrier)
    #pragma unroll
    for (int off = 32; off > 0; off >>= 1)
        acc += __shfl_down(acc, off, 64);
    __shared__ float wsum[WPB];
    if (lane == 0) wsum[widx] = acc;
    __syncthreads();
    if (tid == 0)
        partials[blockIdx.x] = wsum[0] + wsum[1] + wsum[2] + wsum[3];
}

__global__ __launch_bounds__(256) void bl_final(
    const float* __restrict__ p, float* __restrict__ out)
{
    const int tid = threadIdx.x;
    float v = p[tid] + p[tid + 256] + p[tid + 512] + p[tid + 768]; // NBLK == 1024
    #pragma unroll
    for (int off = 32; off > 0; off >>= 1)
        v += __shfl_down(v, off, 64);
    __shared__ float wsum[4];
    if ((tid & 63) == 0) wsum[tid >> 6] = v;
    __syncthreads();
    if (tid == 0)
        out[0] = (wsum[0] + wsum[1] + wsum[2] + wsum[3]) * INV_N;
}

extern "C" void kernel_launch(void* const* d_in, const int* in_sizes, int n_in,
                              void* d_out, int out_size, void* d_ws, size_t ws_size,
                              hipStream_t stream) {
    const float* pred = (const float*)d_in[0];
    const float* tgt  = (const float*)d_in[1];
    float* partials = (float*)d_ws;                 // 1024 floats, fully overwritten
    float* out = (float*)d_out;

    bl_main<<<NBLK, 256, 0, stream>>>(pred, tgt, partials);
    bl_final<<<1, 256, 0, stream>>>(partials, out);
}